// Round 5
// baseline (487.025 us; speedup 1.0000x reference)
//
#include <hip/hip_runtime.h>

typedef unsigned short u16;
typedef unsigned int u32;
typedef __attribute__((ext_vector_type(8))) short bf16x8;
typedef __attribute__((ext_vector_type(4))) float f32x4;

#define BATCH 4
#define SEQ 4096
#define DMODEL 1024
#define DINNER 1024
#define NPROJ 2176          // 2*DINNER + 2*DSTATE
#define MROWS (BATCH*SEQ)   // 16384
#define NCHUNK 64           // chunks per sequence
#define CLEN 64             // chunk length
#define NPAD 2304           // gemm1 N padded to 9*256

__device__ __forceinline__ float bf2f(u16 u) {
    union { u32 i; float f; } v; v.i = ((u32)u) << 16; return v.f;
}
__device__ __forceinline__ u16 f2bf(float f) {
    union { float f; u32 i; } v; v.f = f;
    u32 r = v.i + 0x7FFFu + ((v.i >> 16) & 1u);
    return (u16)(r >> 16);
}
__device__ __forceinline__ float silu_f(float x) { return x / (1.0f + expf(-x)); }

__device__ __forceinline__ void gload8f(const u16* p, float* o) {
    bf16x8 v = *(const bf16x8*)p;
    #pragma unroll
    for (int j = 0; j < 8; ++j) o[j] = bf2f((u16)v[j]);
}

// async global->LDS, 16B per lane; LDS dest = wave-uniform base + lane*16
__device__ __forceinline__ void ld_lds16(const u16* g, u16* l) {
    __builtin_amdgcn_global_load_lds(
        (const __attribute__((address_space(1))) u32*)g,
        (__attribute__((address_space(3))) u32*)l, 16, 0, 0);
}

// ---------------------------------------------------------------------------
// fp32 -> bf16 cast, 8 elems/thread
// ---------------------------------------------------------------------------
__global__ __launch_bounds__(256) void cast_f2b(
    const float* __restrict__ src, u16* __restrict__ dst, int n8)
{
    int i = blockIdx.x * 256 + threadIdx.x;
    if (i >= n8) return;
    size_t o = (size_t)i * 8;
    float4 a = *(const float4*)(src + o);
    float4 b = *(const float4*)(src + o + 4);
    u16 v[8] = {f2bf(a.x), f2bf(a.y), f2bf(a.z), f2bf(a.w),
                f2bf(b.x), f2bf(b.y), f2bf(b.z), f2bf(b.w)};
    *(bf16x8*)(dst + o) = *(bf16x8*)v;
}

// w1 cast with zero pad: src 2176x1024 fp32 -> dst 2304x1024 bf16 (rows>=2176 zero)
__global__ __launch_bounds__(256) void cast_w1p_k(
    const float* __restrict__ src, u16* __restrict__ dst)
{
    int i = blockIdx.x * 256 + threadIdx.x;      // chunk of 8; total NPAD*1024/8
    int row = i >> 7;                            // 128 chunks per row
    size_t o = (size_t)i * 8;
    u16 v[8];
    if (row < NPROJ) {
        float4 a = *(const float4*)(src + o);
        float4 b = *(const float4*)(src + o + 4);
        v[0]=f2bf(a.x); v[1]=f2bf(a.y); v[2]=f2bf(a.z); v[3]=f2bf(a.w);
        v[4]=f2bf(b.x); v[5]=f2bf(b.y); v[6]=f2bf(b.z); v[7]=f2bf(b.w);
    } else {
        #pragma unroll
        for (int j = 0; j < 8; ++j) v[j] = 0;
    }
    *(bf16x8*)(dst + o) = *(bf16x8*)v;
}

// ---------------------------------------------------------------------------
// Decay tables: l2a[n] = log2(a[n]); apw[t][n] = a[n]^t; ainv[t][n] = a[n]^-t
// ---------------------------------------------------------------------------
__global__ __launch_bounds__(256) void tables_k(
    const float* __restrict__ A_param, float* __restrict__ l2a_g,
    float* __restrict__ apw, float* __restrict__ ainv)
{
    __shared__ float l2s[64];
    int tid = threadIdx.x;
    if (tid < 64) {
        float v = -expf(A_param[tid]) * 1.44269504088896340736f;
        l2s[tid] = v;
        l2a_g[tid] = v;
    }
    __syncthreads();
    #pragma unroll
    for (int i = 0; i < 16; ++i) {
        int e = tid * 16 + i;          // e = t*64 + n
        int t = e >> 6, n = e & 63;
        float x = (float)t * l2s[n];
        apw[e]  = exp2f(x);
        ainv[e] = exp2f(-x);
    }
}

// ---------------------------------------------------------------------------
// 8-phase 256x256 NT GEMM (HK-style schedule in plain HIP).
// C[M,Npad] = A[M,1024] @ B[Npad,1024]^T, bf16 in, fp32 accum.
// Race-free uniform-vmcnt calendar (see round-3 header comment) — UNCHANGED.
// ---------------------------------------------------------------------------
#define GK 1024
#define GNT 16   // K tiles of 64

template<typename TO, int GN, int NV, int LDC>
__global__ __launch_bounds__(512, 2) void gemm8p_k(
    const u16* __restrict__ A, const u16* __restrict__ B, TO* __restrict__ C)
{
    __shared__ u16 lds[65536];   // 128 KiB: A[2buf][2half][128*64] then B same

    const int cpx = (GN * 64) >> 3;
    const int bid = blockIdx.x;
    const int swz = (bid & 7) * cpx + (bid >> 3);   // XCD swizzle (nwg%8==0)
    const int bm = swz / GN, bn = swz % GN;
    const int m0 = bm * 256, n0 = bn * 256;

    const int tid = threadIdx.x;
    const int wid = tid >> 6, lane = tid & 63;
    const int wm = wid >> 2, wn = wid & 3;
    const int quad = lane >> 4, l16 = lane & 15;
    const int xsw = (l16 & 7) << 3;                 // read-side XOR (u16 units)

    u16* L = lds;
    const u16* Ab = A + (size_t)m0 * GK;
    const u16* Bb = B + (size_t)n0 * GK;

    auto stage = [&](const u16* gbase, u16* ldsb) {
        {
            int c = tid;
            int row = c >> 3, slot = (c & 7) ^ (row & 7);
            ld_lds16(gbase + (size_t)row * GK + slot * 8,
                     ldsb + ((tid & ~63) << 3));
        }
        {
            int c = 512 + tid;
            int row = c >> 3, slot = (c & 7) ^ (row & 7);
            ld_lds16(gbase + (size_t)row * GK + slot * 8,
                     ldsb + ((512 + (tid & ~63)) << 3));
        }
    };
    auto rdfrag = [&](const u16* base, int rh, int kh) -> bf16x8 {
        return *(const bf16x8*)(base + rh * 64 + ((kh * 32 + quad * 8) ^ xsw));
    };

    bf16x8 aLo[4][2], aHi[4][2], bLo[2][2], bHi[2][2];
    f32x4 acc[8][4] = {};

    // ---- prologue: tile0 fully + both A halves of tile1 in flight
    stage(Ab,                     L);               // A0 t0
    stage(Ab + 128 * GK,          L + 8192);        // A1 t0
    stage(Bb,                     L + 32768);       // B0 t0
    stage(Bb + 128 * GK,          L + 40960);       // B1 t0
    stage(Ab + 64,                L + 16384);       // A0 t1 -> buf1
    stage(Ab + 128 * GK + 64,     L + 24576);       // A1 t1 -> buf1
    asm volatile("s_waitcnt vmcnt(4)" ::: "memory");   // tile0 landed
    __builtin_amdgcn_s_barrier();
    {
        const u16* Ard = L + wm * 8192;
        #pragma unroll
        for (int i = 0; i < 4; ++i)
            #pragma unroll
            for (int kh = 0; kh < 2; ++kh)
                aLo[i][kh] = rdfrag(Ard, i * 16 + l16, kh);
    }

    for (int t = 0; t < GNT; ++t) {
        const int cb = t & 1;
        u16* Acur = L + cb * 16384;
        u16* Anxt = L + (cb ^ 1) * 16384;
        u16* Bnxt = L + 32768 + (cb ^ 1) * 16384;
        const u16* ArdC = Acur + wm * 8192;
        const u16* ArdN = Anxt + wm * 8192;
        const u16* BrdC = L + 32768 + cb * 16384 + (wn >> 1) * 8192;
        const int brh = (wn & 1) * 64;

        // ---------------- q0: MFMA quadrant (lo, lo) ----------------
        #pragma unroll
        for (int j = 0; j < 2; ++j)
            #pragma unroll
            for (int kh = 0; kh < 2; ++kh)
                bLo[j][kh] = rdfrag(BrdC, brh + j * 16 + l16, kh);
        if (t + 1 < GNT) stage(Bb + (t + 1) * 64, Bnxt);            // B0(t+1)
        __builtin_amdgcn_s_barrier();
        asm volatile("s_waitcnt lgkmcnt(0)" ::: "memory");
        __builtin_amdgcn_s_setprio(1);
        #pragma unroll
        for (int kh = 0; kh < 2; ++kh)
            #pragma unroll
            for (int i = 0; i < 4; ++i)
                #pragma unroll
                for (int j = 0; j < 2; ++j)
                    acc[i][j] = __builtin_amdgcn_mfma_f32_16x16x32_bf16(
                        aLo[i][kh], bLo[j][kh], acc[i][j], 0, 0, 0);
        __builtin_amdgcn_s_setprio(0);
        __builtin_amdgcn_s_barrier();

        // ---------------- q1: (lo, hi) ----------------
        #pragma unroll
        for (int j = 0; j < 2; ++j)
            #pragma unroll
            for (int kh = 0; kh < 2; ++kh)
                bHi[j][kh] = rdfrag(BrdC, brh + 32 + j * 16 + l16, kh);
        if (t + 1 < GNT) stage(Bb + 128 * GK + (t + 1) * 64, Bnxt + 8192); // B1(t+1)
        __builtin_amdgcn_s_barrier();
        asm volatile("s_waitcnt lgkmcnt(0)" ::: "memory");
        __builtin_amdgcn_s_setprio(1);
        #pragma unroll
        for (int kh = 0; kh < 2; ++kh)
            #pragma unroll
            for (int i = 0; i < 4; ++i)
                #pragma unroll
                for (int j = 0; j < 2; ++j)
                    acc[i][2 + j] = __builtin_amdgcn_mfma_f32_16x16x32_bf16(
                        aLo[i][kh], bHi[j][kh], acc[i][2 + j], 0, 0, 0);
        __builtin_amdgcn_s_setprio(0);
        __builtin_amdgcn_s_barrier();

        // ---------------- q2: (hi, hi) ----------------
        #pragma unroll
        for (int i = 0; i < 4; ++i)
            #pragma unroll
            for (int kh = 0; kh < 2; ++kh)
                aHi[i][kh] = rdfrag(ArdC, 64 + i * 16 + l16, kh);
        if (t + 2 < GNT) stage(Ab + (t + 2) * 64, Acur);            // A0(t+2)
        if (t + 2 < GNT)      { asm volatile("s_waitcnt vmcnt(6)" ::: "memory"); }
        else if (t + 1 < GNT) { asm volatile("s_waitcnt vmcnt(4)" ::: "memory"); }
        __builtin_amdgcn_s_barrier();
        asm volatile("s_waitcnt lgkmcnt(0)" ::: "memory");
        __builtin_amdgcn_s_setprio(1);
        #pragma unroll
        for (int kh = 0; kh < 2; ++kh)
            #pragma unroll
            for (int i = 0; i < 4; ++i)
                #pragma unroll
                for (int j = 0; j < 2; ++j)
                    acc[4 + i][2 + j] = __builtin_amdgcn_mfma_f32_16x16x32_bf16(
                        aHi[i][kh], bHi[j][kh], acc[4 + i][2 + j], 0, 0, 0);
        __builtin_amdgcn_s_setprio(0);
        __builtin_amdgcn_s_barrier();

        // ---------------- q3: (hi, lo); prefetch next aLo ----------------
        if (t + 1 < GNT) {
            #pragma unroll
            for (int i = 0; i < 4; ++i)
                #pragma unroll
                for (int kh = 0; kh < 2; ++kh)
                    aLo[i][kh] = rdfrag(ArdN, i * 16 + l16, kh);
        }
        if (t + 2 < GNT) stage(Ab + 128 * GK + (t + 2) * 64, Acur + 8192); // A1(t+2)
        if (t + 2 < GNT)      { asm volatile("s_waitcnt vmcnt(4)" ::: "memory"); }
        else if (t + 1 < GNT) { asm volatile("s_waitcnt vmcnt(0)" ::: "memory"); }
        __builtin_amdgcn_s_barrier();
        asm volatile("s_waitcnt lgkmcnt(0)" ::: "memory");
        __builtin_amdgcn_s_setprio(1);
        #pragma unroll
        for (int kh = 0; kh < 2; ++kh)
            #pragma unroll
            for (int i = 0; i < 4; ++i)
                #pragma unroll
                for (int j = 0; j < 2; ++j)
                    acc[4 + i][j] = __builtin_amdgcn_mfma_f32_16x16x32_bf16(
                        aHi[i][kh], bLo[j][kh], acc[4 + i][j], 0, 0, 0);
        __builtin_amdgcn_s_setprio(0);
        __builtin_amdgcn_s_barrier();
    }

    // ---- epilogue: LDS transpose -> coalesced stores ----
    __syncthreads();
    if constexpr (sizeof(TO) == 2) {
        u16* eld = lds;          // viewed as [256][256] bf16
        #pragma unroll
        for (int i = 0; i < 8; ++i)
            #pragma unroll
            for (int j = 0; j < 4; ++j)
                #pragma unroll
                for (int r = 0; r < 4; ++r)
                    eld[(size_t)(wm * 128 + i * 16 + quad * 4 + r) * 256 +
                        wn * 64 + j * 16 + l16] = f2bf(acc[i][j][r]);
        __syncthreads();
        #pragma unroll
        for (int rep = 0; rep < 16; ++rep) {
            int cc = rep * 512 + tid;
            int row = cc >> 5, c8 = (cc & 31) * 8;
            if (n0 + c8 < NV)
                *(bf16x8*)(C + (size_t)(m0 + row) * LDC + n0 + c8) =
                    *(const bf16x8*)(eld + (size_t)row * 256 + c8);
        }
    } else {
        float* eldf = (float*)lds;   // [128][256] fp32, two passes
        #pragma unroll
        for (int h = 0; h < 2; ++h) {
            if (wm == h) {
                #pragma unroll
                for (int i = 0; i < 8; ++i)
                    #pragma unroll
                    for (int j = 0; j < 4; ++j)
                        #pragma unroll
                        for (int r = 0; r < 4; ++r)
                            eldf[(size_t)(i * 16 + quad * 4 + r) * 256 +
                                 wn * 64 + j * 16 + l16] = acc[i][j][r];
            }
            __syncthreads();
            #pragma unroll
            for (int rep = 0; rep < 16; ++rep) {
                int cc = rep * 512 + tid;
                int row = cc >> 6, c4 = (cc & 63) * 4;
                *(float4*)(C + (size_t)(m0 + h * 128 + row) * LDC + n0 + c4) =
                    *(const float4*)(eldf + (size_t)row * 256 + c4);
            }
            __syncthreads();
        }
    }
}

// ---------------------------------------------------------------------------
// Causal depthwise conv (K=4) + bias + SiLU, 8 rows/thread sliding window.
// ---------------------------------------------------------------------------
#define CRPT 8
__global__ __launch_bounds__(256) void conv_k(
    const u16* __restrict__ xBC, const float* __restrict__ conv_w,
    const float* __restrict__ conv_b, u16* __restrict__ xact)
{
    int o = blockIdx.x * 256 + threadIdx.x;   // MROWS/CRPT * 128 total
    int c0 = (o & 127) * 8;
    int rg = o >> 7;
    int row0 = rg * CRPT;
    int l0 = row0 & (SEQ - 1);                // SEQ % CRPT == 0: no seq crossing

    float4 wv[8];
    #pragma unroll
    for (int j = 0; j < 8; ++j)
        wv[j] = *(const float4*)(conv_w + (c0 + j) * 4);
    float bias[8];
    {
        float4 b0 = *(const float4*)(conv_b + c0);
        float4 b1 = *(const float4*)(conv_b + c0 + 4);
        bias[0]=b0.x; bias[1]=b0.y; bias[2]=b0.z; bias[3]=b0.w;
        bias[4]=b1.x; bias[5]=b1.y; bias[6]=b1.z; bias[7]=b1.w;
    }

    float win[3][8];
    #pragma unroll
    for (int k = 0; k < 3; ++k) {
        if (l0 - 3 + k < 0) {
            #pragma unroll
            for (int j = 0; j < 8; ++j) win[k][j] = 0.f;
        } else {
            gload8f(xBC + (size_t)(row0 - 3 + k) * NPROJ + c0, win[k]);
        }
    }
    #pragma unroll
    for (int r = 0; r < CRPT; ++r) {
        float cur[8];
        gload8f(xBC + (size_t)(row0 + r) * NPROJ + c0, cur);
        u16 outv[8];
        #pragma unroll
        for (int j = 0; j < 8; ++j) {
            float acc = bias[j]
                + win[0][j] * wv[j].x + win[1][j] * wv[j].y
                + win[2][j] * wv[j].z + cur[j]    * wv[j].w;
            outv[j] = f2bf(silu_f(acc));
        }
        *(bf16x8*)(xact + (size_t)(row0 + r) * DINNER + c0) = *(bf16x8*)outv;
        #pragma unroll
        for (int j = 0; j < 8; ++j) {
            win[0][j] = win[1][j]; win[1][j] = win[2][j]; win[2][j] = cur[j];
        }
    }
}

// ---------------------------------------------------------------------------
// Pass A: intra-chunk SSD.  Grid (dg=16, c=64, b=4); 256 threads, 4 waves.
// S output bf16 (u16).
// ---------------------------------------------------------------------------
__global__ __launch_bounds__(256) void ssd_intra_k(
    const u16* __restrict__ xact, u16* __restrict__ xBC,
    u16* __restrict__ Sh, const float* __restrict__ apw,
    const float* __restrict__ ainv)
{
    __shared__ u16 Pl[64][72];       // P[t][n] = C_t a^t
    __shared__ u16 Ql[64][72];       // Q[s][n] = B_s a^-s, then Ghi[t][s]
    __shared__ u16 Gl[64][72];       // Glo[t][s]
    __shared__ u16 Qt[64][72];       // Qt[n][s] = B_s a^{63-s}
    __shared__ u16 Xt[64][72];       // X^T [d][s]

    const int dg = blockIdx.x, c = blockIdx.y, b = blockIdx.z;
    const int dcol = dg * 64;
    const int l0 = c * CLEN;
    const int tid = threadIdx.x;
    const int w = tid >> 6, lane = tid & 63;
    const int quad = lane >> 4, l16 = lane & 15;
    const int tstrip = 16 * w;

    // stage B/C -> P, Q, Qt
    {
        const int st_t = tid >> 3, st_n8 = (tid & 7) * 8;
        #pragma unroll
        for (int rep = 0; rep < 2; ++rep) {
            int t = rep * 32 + st_t;
            size_t row = (size_t)(b * SEQ + l0 + t) * NPROJ;
            float Bv[8], Cv[8];
            gload8f(xBC + row + 2048 + st_n8, Bv);
            gload8f(xBC + row + 2112 + st_n8, Cv);
            float4 aw0 = *(const float4*)&apw[t * 64 + st_n8];
            float4 aw1 = *(const float4*)&apw[t * 64 + st_n8 + 4];
            float4 ai0 = *(const float4*)&ainv[t * 64 + st_n8];
            float4 ai1 = *(const float4*)&ainv[t * 64 + st_n8 + 4];
            float4 ar0 = *(const float4*)&apw[(63 - t) * 64 + st_n8];
            float4 ar1 = *(const float4*)&apw[(63 - t) * 64 + st_n8 + 4];
            float aw[8] = {aw0.x,aw0.y,aw0.z,aw0.w,aw1.x,aw1.y,aw1.z,aw1.w};
            float ai[8] = {ai0.x,ai0.y,ai0.z,ai0.w,ai1.x,ai1.y,ai1.z,ai1.w};
            float ar[8] = {ar0.x,ar0.y,ar0.z,ar0.w,ar1.x,ar1.y,ar1.z,ar1.w};
            u16 p8[8], q8[8];
            #pragma unroll
            for (int j = 0; j < 8; ++j) {
                p8[j] = f2bf(Cv[j] * aw[j]);
                q8[j] = f2bf(Bv[j] * ai[j]);
            }
            *(bf16x8*)&Pl[t][st_n8] = *(bf16x8*)p8;
            *(bf16x8*)&Ql[t][st_n8] = *(bf16x8*)q8;
            #pragma unroll
            for (int j = 0; j < 8; ++j)
                Qt[st_n8 + j][t] = f2bf(Bv[j] * ar[j]);
        }
    }
    // stage X transposed
    {
        #pragma unroll
        for (int rep = 0; rep < 2; ++rep) {
            int idx = rep * 256 + tid;          // 0..511
            int xt_t = idx >> 3, xt_d8 = (idx & 7) * 8;
            float xv[8];
            gload8f(xact + (size_t)(b * SEQ + l0 + xt_t) * DINNER + dcol + xt_d8, xv);
            #pragma unroll
            for (int j = 0; j < 8; ++j) Xt[xt_d8 + j][xt_t] = f2bf(xv[j]);
        }
    }
    __syncthreads();

    // ---- G = P Q^T (per wave: 16-t strip) ----
    bf16x8 af0 = *(const bf16x8*)&Pl[tstrip + l16][0  + quad * 8];
    bf16x8 af1 = *(const bf16x8*)&Pl[tstrip + l16][32 + quad * 8];
    f32x4 g[4] = {};
    #pragma unroll
    for (int j4 = 0; j4 < 4; ++j4) {
        bf16x8 b0 = *(const bf16x8*)&Ql[j4 * 16 + l16][0  + quad * 8];
        bf16x8 b1 = *(const bf16x8*)&Ql[j4 * 16 + l16][32 + quad * 8];
        g[j4] = __builtin_amdgcn_mfma_f32_16x16x32_bf16(af0, b0, g[j4], 0, 0, 0);
        g[j4] = __builtin_amdgcn_mfma_f32_16x16x32_bf16(af1, b1, g[j4], 0, 0, 0);
    }
    __syncthreads();

    // ---- mask (s<=t) + hi/lo split: Ghi->Ql, Glo->Gl ----
    #pragma unroll
    for (int j4 = 0; j4 < 4; ++j4) {
        #pragma unroll
        for (int r = 0; r < 4; ++r) {
            int t = tstrip + quad * 4 + r;
            int s = j4 * 16 + l16;
            float val = (s <= t) ? g[j4][r] : 0.f;
            u16 hi = f2bf(val);
            Ql[t][s] = hi;
            Gl[t][s] = f2bf(val - bf2f(hi));
        }
    }
    __syncthreads();

    // ---- Y strip [16t x 64d] and S strip [16n x 64d] ----
    bf16x8 gh0 = *(const bf16x8*)&Ql[tstrip + l16][0  + quad * 8];
    bf16x8 gh1 = *(const bf16x8*)&Ql[tstrip + l16][32 + quad * 8];
    bf16x8 gl0 = *(const bf16x8*)&Gl[tstrip + l16][0  + quad * 8];
    bf16x8 gl1 = *(const bf16x8*)&Gl[tstrip + l16][32 + quad * 8];
    bf16x8 qt0 = *(const bf16x8*)&Qt[tstrip + l16][0  + quad * 8];
    bf16x8 qt1 = *(const bf16x8*)&Qt[tstrip + l16][32 + quad * 8];

    #pragma unroll
    for (int dt = 0; dt < 4; ++dt) {
        bf16x8 x0 = *(const bf16x8*)&Xt[dt * 16 + l16][0  + quad * 8];
        bf16x8 x1 = *(const bf16x8*)&Xt[dt * 16 + l16][32 + quad * 8];
        f32x4 y = {};
        y = __builtin_amdgcn_mfma_f32_16x16x32_bf16(gh0, x0, y, 0, 0, 0);
        y = __builtin_amdgcn_mfma_f32_16x16x32_bf16(gh1, x1, y, 0, 0, 0);
        y = __builtin_amdgcn_mfma_f32_16x16x32_bf16(gl0, x0, y, 0, 0, 0);
        y = __builtin_amdgcn_mfma_f32_16x16x32_bf16(gl1, x1, y, 0, 0, 0);
        f32x4 s4 = {};
        s4 = __builtin_amdgcn_mfma_f32_16x16x32_bf16(qt0, x0, s4, 0, 0, 0);
        s4 = __builtin_amdgcn_mfma_f32_16x16x32_bf16(qt1, x1, s4, 0, 0, 0);
        #pragma unroll
        for (int r = 0; r < 4; ++r) {
            int t = tstrip + quad * 4 + r;       // y row
            xBC[(size_t)(b * SEQ + l0 + t) * NPROJ + dcol + dt * 16 + l16] = f2bf(y[r]);
            int n = tstrip + quad * 4 + r;       // s row
            Sh[((size_t)((b * NCHUNK + c) * 64 + n)) * 1024 + dcol + dt * 16 + l16] = f2bf(s4[r]);
        }
    }
}

// ---------------------------------------------------------------------------
// Pass B: inter-chunk state scan, in place on Sh (bf16, fp32 carry).
// ---------------------------------------------------------------------------
__global__ __launch_bounds__(256) void state_scan_k(
    u16* __restrict__ Sh, const float* __restrict__ l2a)
{
    int gid = blockIdx.x * 256 + threadIdx.x;    // 262144 total
    int b = gid >> 16, r = gid & 65535, n = r >> 10;
    float a64 = exp2f(64.f * l2a[n]);
    float v = 0.f;
    size_t base = ((size_t)b << 22) + r;
    for (int c = 0; c < NCHUNK; ++c) {
        size_t addr = base + ((size_t)c << 16);
        float s = bf2f(Sh[addr]);
        Sh[addr] = f2bf(v);
        v = fmaf(v, a64, s);
    }
}

// ---------------------------------------------------------------------------
// Fused Pass C + gate + LayerNorm.  One block per (chunk c, batch b),
// 512 threads (8 waves), 1 block/CU (148 KB LDS).
// Phase 1: stage P' = C_t a^(t+1), V^T; MFMA correction (wave w owns d-strip
//          w*128..+127).  [launch_bounds (512,1): no VGPR cap -> no spill]
// Phase 2: barrier; write corr bf16 into dead Vt space, layout [64][1040]
//          with d ^= quad<<4 bank swizzle (write 2-way = free); barrier;
//          threads remap to (row=tid>>3, c8=tid&7): all vector 16B access:
//          g = (y + corr)*silu(z) fp32 -> stats; g cached bf16 in same slot;
//          8-lane shfl reduce; normalize + coalesced store.
// ---------------------------------------------------------------------------
__global__ __launch_bounds__(512, 1) void inter_gate_k(
    const u16* __restrict__ xBC, const u16* __restrict__ Sh,
    const float* __restrict__ apw, const float* __restrict__ l2a,
    const float* __restrict__ ln_w, const float* __restrict__ ln_b,
    u16* __restrict__ yn)
{
    __shared__ u16 Pl[64][72];        // P'[t][n]   (9216 B)
    __shared__ u16 Vt[1024][68];      // V[d][n]; reused as corr/g [64][1040]

    const int c = blockIdx.x, b = blockIdx.y;
    const int tid = threadIdx.x;
    const int w = tid >> 6, lane = tid & 63;
    const int quad = lane >> 4, l16 = lane & 15;
    const int dW = w * 128;
    const int brow = b * SEQ + c * CLEN;
    u16* Lc = &Vt[0][0];              // corr view, pitch 1040 u16

    // ---- stage P' = C_t * a^(t+1): one (t, n8) chunk per thread ----
    {
        const int st_t = tid >> 3, st_n8 = (tid & 7) * 8;
        float Cv[8];
        gload8f(xBC + (size_t)(brow + st_t) * NPROJ + 2112 + st_n8, Cv);
        float4 aw0 = *(const float4*)&apw[st_t * 64 + st_n8];
        float4 aw1 = *(const float4*)&apw[st_t * 64 + st_n8 + 4];
        float aw[8] = {aw0.x,aw0.y,aw0.z,aw0.w,aw1.x,aw1.y,aw1.z,aw1.w};
        u16 p8[8];
        #pragma unroll
        for (int j = 0; j < 8; ++j)
            p8[j] = f2bf(Cv[j] * aw[j] * exp2f(l2a[st_n8 + j]));
        *(bf16x8*)&Pl[st_t][st_n8] = *(bf16x8*)p8;
    }
    // ---- stage V transposed: 2 subtiles (8n x 8d) per thread ----
    {
        const size_t vbase = (size_t)((b * NCHUNK + c) * 64) * 1024;
        const int n0 = (tid & 7) * 8;
        #pragma unroll
        for (int rep = 0; rep < 2; ++rep) {
            int d_blk = (tid >> 3) + rep * 64;      // 0..127
            bf16x8 vin[8];
            #pragma unroll
            for (int jj = 0; jj < 8; ++jj)
                vin[jj] = *(const bf16x8*)&Sh[vbase + (size_t)(n0 + jj) * 1024 + d_blk * 8];
            #pragma unroll
            for (int jj2 = 0; jj2 < 8; ++jj2) {
                u16 outv[8];
                #pragma unroll
                for (int jj = 0; jj < 8; ++jj) outv[jj] = (u16)vin[jj][jj2];
                *(bf16x8*)&Vt[d_blk * 8 + jj2][n0] = *(bf16x8*)outv;
            }
        }
    }
    __syncthreads();

    // ---- correction MFMA: acc[i][j] = P'[16i..][64n] x V[n][dW+16j..] ----
    bf16x8 pa[4][2];
    #pragma unroll
    for (int i = 0; i < 4; ++i)
        #pragma unroll
        for (int kh = 0; kh < 2; ++kh)
            pa[i][kh] = *(const bf16x8*)&Pl[i * 16 + l16][kh * 32 + quad * 8];

    f32x4 acc[4][8] = {};
    #pragma unroll
    for (int j = 0; j < 8; ++j) {
        bf16x8 pb0 = *(const bf16x8*)&Vt[dW + j * 16 + l16][quad * 8];
        bf16x8 pb1 = *(const bf16x8*)&Vt[dW + j * 16 + l16][32 + quad * 8];
        #pragma unroll
        for (int i = 0; i < 4; ++i) {
            acc[i][j] = __builtin_amdgcn_mfma_f32_16x16x32_bf16(pa[i][0], pb0, acc[i][j], 0, 0, 0);
            acc[i][j] = __builtin_amdgcn_mfma_f32_16x16x32_bf16(pa[i][1], pb1, acc[i][j], 0, 0, 0);
        }
    }
    __syncthreads();   // all waves done reading Vt before corr overwrites it

    // ---- write corr (bf16) into Lc[t][d ^ (quad<<4)], pitch 1040 ----
    #pragma unroll
    for (int i = 0; i < 4; ++i)
        #pragma unroll
        for (int j = 0; j < 8; ++j)
            #pragma unroll
            for (int r = 0; r < 4; ++r) {
                int t = i * 16 + quad * 4 + r;
                int d = dW + j * 16 + l16;
                Lc[t * 1040 + (d ^ (quad << 4))] = f2bf(acc[i][j][r]);
            }
    __syncthreads();

    // ---- phase 2: (row, c8) remap; all-vector gate + LN ----
    const int row = tid >> 3, c8 = tid & 7;
    const int qx = ((row >> 2) & 3) << 4;            // un-swizzle for this row
    const size_t rb = (size_t)(brow + row) * NPROJ;
    u16* Lrow = Lc + row * 1040;
    float s1 = 0.f, s2 = 0.f;
    #pragma unroll
    for (int k = 0; k < 16; ++k) {
        int d0 = c8 * 8 + k * 64;
        float yv[8], zv[8], cv[8];
        gload8f(xBC + rb + d0, yv);
        gload8f(xBC + rb + 1024 + d0, zv);
        gload8f(Lrow + (d0 ^ qx), cv);
        u16 g8[8];
        #pragma unroll
        for (int jj = 0; jj < 8; ++jj) {
            float g = (yv[jj] + cv[jj]) * silu_f(zv[jj]);
            s1 += g; s2 += g * g;
            g8[jj] = f2bf(g);
        }
        *(bf16x8*)(Lrow + (d0 ^ qx)) = *(bf16x8*)g8;   // own slot: no race
    }
    #pragma unroll
    for (int off = 1; off < 8; off <<= 1) {
        s1 += __shfl_xor(s1, off);
        s2 += __shfl_xor(s2, off);
    }
    float mu = s1 * (1.0f / DINNER);
    float var = s2 * (1.0f / DINNER) - mu * mu;
    float inv = rsqrtf(var + 1e-5f);

    const size_t ob = (size_t)(brow + row) * DINNER;
    #pragma unroll
    for (int k = 0; k < 16; ++k) {
        int d0 = c8 * 8 + k * 64;
        float gv[8];
        gload8f(Lrow + (d0 ^ qx), gv);
        float4 w0 = *(const float4*)(ln_w + d0);
        float4 w1 = *(const float4*)(ln_w + d0 + 4);
        float4 b0 = *(const float4*)(ln_b + d0);
        float4 b1 = *(const float4*)(ln_b + d0 + 4);
        float lw[8] = {w0.x,w0.y,w0.z,w0.w,w1.x,w1.y,w1.z,w1.w};
        float lb[8] = {b0.x,b0.y,b0.z,b0.w,b1.x,b1.y,b1.z,b1.w};
        u16 o8[8];
        #pragma unroll
        for (int jj = 0; jj < 8; ++jj)
            o8[jj] = f2bf((gv[jj] - mu) * inv * lw[jj] + lb[jj]);
        *(bf16x8*)(yn + ob + d0) = *(bf16x8*)o8;
    }
}

// ---------------------------------------------------------------------------
extern "C" void kernel_launch(void* const* d_in, const int* in_sizes, int n_in,
                              void* d_out, int out_size, void* d_ws, size_t ws_size,
                              hipStream_t stream) {
    const float* x   = (const float*)d_in[0];
    const float* w1  = (const float*)d_in[1];
    const float* cw  = (const float*)d_in[2];
    const float* cb  = (const float*)d_in[3];
    const float* ap  = (const float*)d_in[4];
    const float* lnw = (const float*)d_in[5];
    const float* lnb = (const float*)d_in[6];
    const float* w2  = (const float*)d_in[7];
    float* out = (float*)d_out;

    // ws layout (~107 MiB):
    u16* xBC   = (u16*)d_ws;                             // MROWS x 2176
    u16* xact  = xBC + (size_t)MROWS * NPROJ;            // MROWS x 1024 (x_bf alias)
    u16* x_bf  = xact;                                   // dead once conv writes xact
    u16* w2_bf = xact + (size_t)MROWS * DINNER;          // 1024x1024
    float* l2a  = (float*)(w2_bf + (size_t)DMODEL * DINNER);  // 64
    float* apw  = l2a + 64;                              // 64x64
    float* ainv = apw + 4096;                            // 64x64
    // w1p (padded weights, 4.7MB) then Sh (bf16 S/V, 33.5MB) park in d_out:
    // w1p dead after gemm1; Sh written by pass A, consumed by inter_gate
    // before gemm2 overwrites d_out with the final output.
    u16* w1p = (u16*)d_out;                              // 2304x1024 bf16
    u16* Sh  = (u16*)d_out;                              // 4 x 64 x 64 x 1024 bf16

    cast_f2b<<<(MROWS * DMODEL / 8) / 256, 256, 0, stream>>>(x, x_bf, MROWS * DMODEL / 8);
    cast_w1p_k<<<(NPAD * DMODEL / 8) / 256, 256, 0, stream>>>(w1, w1p);
    cast_f2b<<<(DMODEL * DINNER / 8) / 256, 256, 0, stream>>>(w2, w2_bf, DMODEL * DINNER / 8);
    tables_k<<<1, 256, 0, stream>>>(ap, l2a, apw, ainv);

    gemm8p_k<u16, 9, NPROJ, NPROJ><<<9 * 64, 512, 0, stream>>>(x_bf, w1p, xBC);
    conv_k<<<(MROWS / CRPT * 128) / 256, 256, 0, stream>>>(xBC, cw, cb, xact);

    ssd_intra_k<<<dim3(16, NCHUNK, BATCH), 256, 0, stream>>>(xact, xBC, Sh, apw, ainv);
    state_scan_k<<<1024, 256, 0, stream>>>(Sh, l2a);
    inter_gate_k<<<dim3(NCHUNK, BATCH), 512, 0, stream>>>(xBC, Sh, apw, l2a, lnw, lnb, xact);

    gemm8p_k<float, 4, DMODEL, DMODEL><<<4 * 64, 512, 0, stream>>>(xact, w2_bf, out);
}

// Round 6
// 372.399 us; speedup vs baseline: 1.3078x; 1.3078x over previous
//
#include <hip/hip_runtime.h>

typedef unsigned short u16;
typedef unsigned int u32;
typedef __attribute__((ext_vector_type(8))) short bf16x8;
typedef __attribute__((ext_vector_type(4))) float f32x4;

#define BATCH 4
#define SEQ 4096
#define DMODEL 1024
#define DINNER 1024
#define NPROJ 2176          // 2*DINNER + 2*DSTATE
#define MROWS (BATCH*SEQ)   // 16384
#define NCHUNK 64           // chunks per sequence
#define CLEN 64             // chunk length
#define NPAD 2304           // gemm1 N padded to 9*256

__device__ __forceinline__ float bf2f(u16 u) {
    union { u32 i; float f; } v; v.i = ((u32)u) << 16; return v.f;
}
__device__ __forceinline__ u16 f2bf(float f) {
    union { float f; u32 i; } v; v.f = f;
    u32 r = v.i + 0x7FFFu + ((v.i >> 16) & 1u);
    return (u16)(r >> 16);
}
__device__ __forceinline__ float silu_f(float x) { return x / (1.0f + expf(-x)); }

__device__ __forceinline__ void gload8f(const u16* p, float* o) {
    bf16x8 v = *(const bf16x8*)p;
    #pragma unroll
    for (int j = 0; j < 8; ++j) o[j] = bf2f((u16)v[j]);
}

// async global->LDS, 16B per lane; LDS dest = wave-uniform base + lane*16
__device__ __forceinline__ void ld_lds16(const u16* g, u16* l) {
    __builtin_amdgcn_global_load_lds(
        (const __attribute__((address_space(1))) u32*)g,
        (__attribute__((address_space(3))) u32*)l, 16, 0, 0);
}

// ---------------------------------------------------------------------------
// fp32 -> bf16 cast, 8 elems/thread
// ---------------------------------------------------------------------------
__global__ __launch_bounds__(256) void cast_f2b(
    const float* __restrict__ src, u16* __restrict__ dst, int n8)
{
    int i = blockIdx.x * 256 + threadIdx.x;
    if (i >= n8) return;
    size_t o = (size_t)i * 8;
    float4 a = *(const float4*)(src + o);
    float4 b = *(const float4*)(src + o + 4);
    u16 v[8] = {f2bf(a.x), f2bf(a.y), f2bf(a.z), f2bf(a.w),
                f2bf(b.x), f2bf(b.y), f2bf(b.z), f2bf(b.w)};
    *(bf16x8*)(dst + o) = *(bf16x8*)v;
}

// w1 cast with zero pad: src 2176x1024 fp32 -> dst 2304x1024 bf16 (rows>=2176 zero)
__global__ __launch_bounds__(256) void cast_w1p_k(
    const float* __restrict__ src, u16* __restrict__ dst)
{
    int i = blockIdx.x * 256 + threadIdx.x;      // chunk of 8; total NPAD*1024/8
    int row = i >> 7;                            // 128 chunks per row
    size_t o = (size_t)i * 8;
    u16 v[8];
    if (row < NPROJ) {
        float4 a = *(const float4*)(src + o);
        float4 b = *(const float4*)(src + o + 4);
        v[0]=f2bf(a.x); v[1]=f2bf(a.y); v[2]=f2bf(a.z); v[3]=f2bf(a.w);
        v[4]=f2bf(b.x); v[5]=f2bf(b.y); v[6]=f2bf(b.z); v[7]=f2bf(b.w);
    } else {
        #pragma unroll
        for (int j = 0; j < 8; ++j) v[j] = 0;
    }
    *(bf16x8*)(dst + o) = *(bf16x8*)v;
}

// ---------------------------------------------------------------------------
// Decay tables: l2a[n] = log2(a[n]); apw[t][n] = a[n]^t; ainv[t][n] = a[n]^-t
// ---------------------------------------------------------------------------
__global__ __launch_bounds__(256) void tables_k(
    const float* __restrict__ A_param, float* __restrict__ l2a_g,
    float* __restrict__ apw, float* __restrict__ ainv)
{
    __shared__ float l2s[64];
    int tid = threadIdx.x;
    if (tid < 64) {
        float v = -expf(A_param[tid]) * 1.44269504088896340736f;
        l2s[tid] = v;
        l2a_g[tid] = v;
    }
    __syncthreads();
    #pragma unroll
    for (int i = 0; i < 16; ++i) {
        int e = tid * 16 + i;          // e = t*64 + n
        int t = e >> 6, n = e & 63;
        float x = (float)t * l2s[n];
        apw[e]  = exp2f(x);
        ainv[e] = exp2f(-x);
    }
}

// ---------------------------------------------------------------------------
// 8-phase 256x256 NT GEMM (HK-style schedule in plain HIP).
// C[M,Npad] = A[M,1024] @ B[Npad,1024]^T, bf16 in, fp32 accum.
// Race-free uniform-vmcnt calendar (see round-3 header comment) — UNCHANGED.
// ---------------------------------------------------------------------------
#define GK 1024
#define GNT 16   // K tiles of 64

template<typename TO, int GN, int NV, int LDC>
__global__ __launch_bounds__(512, 2) void gemm8p_k(
    const u16* __restrict__ A, const u16* __restrict__ B, TO* __restrict__ C)
{
    __shared__ u16 lds[65536];   // 128 KiB: A[2buf][2half][128*64] then B same

    const int cpx = (GN * 64) >> 3;
    const int bid = blockIdx.x;
    const int swz = (bid & 7) * cpx + (bid >> 3);   // XCD swizzle (nwg%8==0)
    const int bm = swz / GN, bn = swz % GN;
    const int m0 = bm * 256, n0 = bn * 256;

    const int tid = threadIdx.x;
    const int wid = tid >> 6, lane = tid & 63;
    const int wm = wid >> 2, wn = wid & 3;
    const int quad = lane >> 4, l16 = lane & 15;
    const int xsw = (l16 & 7) << 3;                 // read-side XOR (u16 units)

    u16* L = lds;
    const u16* Ab = A + (size_t)m0 * GK;
    const u16* Bb = B + (size_t)n0 * GK;

    auto stage = [&](const u16* gbase, u16* ldsb) {
        {
            int c = tid;
            int row = c >> 3, slot = (c & 7) ^ (row & 7);
            ld_lds16(gbase + (size_t)row * GK + slot * 8,
                     ldsb + ((tid & ~63) << 3));
        }
        {
            int c = 512 + tid;
            int row = c >> 3, slot = (c & 7) ^ (row & 7);
            ld_lds16(gbase + (size_t)row * GK + slot * 8,
                     ldsb + ((512 + (tid & ~63)) << 3));
        }
    };
    auto rdfrag = [&](const u16* base, int rh, int kh) -> bf16x8 {
        return *(const bf16x8*)(base + rh * 64 + ((kh * 32 + quad * 8) ^ xsw));
    };

    bf16x8 aLo[4][2], aHi[4][2], bLo[2][2], bHi[2][2];
    f32x4 acc[8][4] = {};

    // ---- prologue: tile0 fully + both A halves of tile1 in flight
    stage(Ab,                     L);               // A0 t0
    stage(Ab + 128 * GK,          L + 8192);        // A1 t0
    stage(Bb,                     L + 32768);       // B0 t0
    stage(Bb + 128 * GK,          L + 40960);       // B1 t0
    stage(Ab + 64,                L + 16384);       // A0 t1 -> buf1
    stage(Ab + 128 * GK + 64,     L + 24576);       // A1 t1 -> buf1
    asm volatile("s_waitcnt vmcnt(4)" ::: "memory");   // tile0 landed
    __builtin_amdgcn_s_barrier();
    {
        const u16* Ard = L + wm * 8192;
        #pragma unroll
        for (int i = 0; i < 4; ++i)
            #pragma unroll
            for (int kh = 0; kh < 2; ++kh)
                aLo[i][kh] = rdfrag(Ard, i * 16 + l16, kh);
    }

    for (int t = 0; t < GNT; ++t) {
        const int cb = t & 1;
        u16* Acur = L + cb * 16384;
        u16* Anxt = L + (cb ^ 1) * 16384;
        u16* Bnxt = L + 32768 + (cb ^ 1) * 16384;
        const u16* ArdC = Acur + wm * 8192;
        const u16* ArdN = Anxt + wm * 8192;
        const u16* BrdC = L + 32768 + cb * 16384 + (wn >> 1) * 8192;
        const int brh = (wn & 1) * 64;

        // ---------------- q0: MFMA quadrant (lo, lo) ----------------
        #pragma unroll
        for (int j = 0; j < 2; ++j)
            #pragma unroll
            for (int kh = 0; kh < 2; ++kh)
                bLo[j][kh] = rdfrag(BrdC, brh + j * 16 + l16, kh);
        if (t + 1 < GNT) stage(Bb + (t + 1) * 64, Bnxt);            // B0(t+1)
        __builtin_amdgcn_s_barrier();
        asm volatile("s_waitcnt lgkmcnt(0)" ::: "memory");
        __builtin_amdgcn_s_setprio(1);
        #pragma unroll
        for (int kh = 0; kh < 2; ++kh)
            #pragma unroll
            for (int i = 0; i < 4; ++i)
                #pragma unroll
                for (int j = 0; j < 2; ++j)
                    acc[i][j] = __builtin_amdgcn_mfma_f32_16x16x32_bf16(
                        aLo[i][kh], bLo[j][kh], acc[i][j], 0, 0, 0);
        __builtin_amdgcn_s_setprio(0);
        __builtin_amdgcn_s_barrier();

        // ---------------- q1: (lo, hi) ----------------
        #pragma unroll
        for (int j = 0; j < 2; ++j)
            #pragma unroll
            for (int kh = 0; kh < 2; ++kh)
                bHi[j][kh] = rdfrag(BrdC, brh + 32 + j * 16 + l16, kh);
        if (t + 1 < GNT) stage(Bb + 128 * GK + (t + 1) * 64, Bnxt + 8192); // B1(t+1)
        __builtin_amdgcn_s_barrier();
        asm volatile("s_waitcnt lgkmcnt(0)" ::: "memory");
        __builtin_amdgcn_s_setprio(1);
        #pragma unroll
        for (int kh = 0; kh < 2; ++kh)
            #pragma unroll
            for (int i = 0; i < 4; ++i)
                #pragma unroll
                for (int j = 0; j < 2; ++j)
                    acc[i][2 + j] = __builtin_amdgcn_mfma_f32_16x16x32_bf16(
                        aLo[i][kh], bHi[j][kh], acc[i][2 + j], 0, 0, 0);
        __builtin_amdgcn_s_setprio(0);
        __builtin_amdgcn_s_barrier();

        // ---------------- q2: (hi, hi) ----------------
        #pragma unroll
        for (int i = 0; i < 4; ++i)
            #pragma unroll
            for (int kh = 0; kh < 2; ++kh)
                aHi[i][kh] = rdfrag(ArdC, 64 + i * 16 + l16, kh);
        if (t + 2 < GNT) stage(Ab + (t + 2) * 64, Acur);            // A0(t+2)
        if (t + 2 < GNT)      { asm volatile("s_waitcnt vmcnt(6)" ::: "memory"); }
        else if (t + 1 < GNT) { asm volatile("s_waitcnt vmcnt(4)" ::: "memory"); }
        __builtin_amdgcn_s_barrier();
        asm volatile("s_waitcnt lgkmcnt(0)" ::: "memory");
        __builtin_amdgcn_s_setprio(1);
        #pragma unroll
        for (int kh = 0; kh < 2; ++kh)
            #pragma unroll
            for (int i = 0; i < 4; ++i)
                #pragma unroll
                for (int j = 0; j < 2; ++j)
                    acc[4 + i][2 + j] = __builtin_amdgcn_mfma_f32_16x16x32_bf16(
                        aHi[i][kh], bHi[j][kh], acc[4 + i][2 + j], 0, 0, 0);
        __builtin_amdgcn_s_setprio(0);
        __builtin_amdgcn_s_barrier();

        // ---------------- q3: (hi, lo); prefetch next aLo ----------------
        if (t + 1 < GNT) {
            #pragma unroll
            for (int i = 0; i < 4; ++i)
                #pragma unroll
                for (int kh = 0; kh < 2; ++kh)
                    aLo[i][kh] = rdfrag(ArdN, i * 16 + l16, kh);
        }
        if (t + 2 < GNT) stage(Ab + 128 * GK + (t + 2) * 64, Acur + 8192); // A1(t+2)
        if (t + 2 < GNT)      { asm volatile("s_waitcnt vmcnt(4)" ::: "memory"); }
        else if (t + 1 < GNT) { asm volatile("s_waitcnt vmcnt(0)" ::: "memory"); }
        __builtin_amdgcn_s_barrier();
        asm volatile("s_waitcnt lgkmcnt(0)" ::: "memory");
        __builtin_amdgcn_s_setprio(1);
        #pragma unroll
        for (int kh = 0; kh < 2; ++kh)
            #pragma unroll
            for (int i = 0; i < 4; ++i)
                #pragma unroll
                for (int j = 0; j < 2; ++j)
                    acc[4 + i][j] = __builtin_amdgcn_mfma_f32_16x16x32_bf16(
                        aHi[i][kh], bLo[j][kh], acc[4 + i][j], 0, 0, 0);
        __builtin_amdgcn_s_setprio(0);
        __builtin_amdgcn_s_barrier();
    }

    // ---- epilogue: LDS transpose -> coalesced stores ----
    __syncthreads();
    if constexpr (sizeof(TO) == 2) {
        u16* eld = lds;          // viewed as [256][256] bf16
        #pragma unroll
        for (int i = 0; i < 8; ++i)
            #pragma unroll
            for (int j = 0; j < 4; ++j)
                #pragma unroll
                for (int r = 0; r < 4; ++r)
                    eld[(size_t)(wm * 128 + i * 16 + quad * 4 + r) * 256 +
                        wn * 64 + j * 16 + l16] = f2bf(acc[i][j][r]);
        __syncthreads();
        #pragma unroll
        for (int rep = 0; rep < 16; ++rep) {
            int cc = rep * 512 + tid;
            int row = cc >> 5, c8 = (cc & 31) * 8;
            if (n0 + c8 < NV)
                *(bf16x8*)(C + (size_t)(m0 + row) * LDC + n0 + c8) =
                    *(const bf16x8*)(eld + (size_t)row * 256 + c8);
        }
    } else {
        float* eldf = (float*)lds;   // [128][256] fp32, two passes
        #pragma unroll
        for (int h = 0; h < 2; ++h) {
            if (wm == h) {
                #pragma unroll
                for (int i = 0; i < 8; ++i)
                    #pragma unroll
                    for (int j = 0; j < 4; ++j)
                        #pragma unroll
                        for (int r = 0; r < 4; ++r)
                            eldf[(size_t)(i * 16 + quad * 4 + r) * 256 +
                                 wn * 64 + j * 16 + l16] = acc[i][j][r];
            }
            __syncthreads();
            #pragma unroll
            for (int rep = 0; rep < 16; ++rep) {
                int cc = rep * 512 + tid;
                int row = cc >> 6, c4 = (cc & 63) * 4;
                *(float4*)(C + (size_t)(m0 + h * 128 + row) * LDC + n0 + c4) =
                    *(const float4*)(eldf + (size_t)row * 256 + c4);
            }
            __syncthreads();
        }
    }
}

// ---------------------------------------------------------------------------
// Causal depthwise conv (K=4) + bias + SiLU, 8 rows/thread sliding window.
// ---------------------------------------------------------------------------
#define CRPT 8
__global__ __launch_bounds__(256) void conv_k(
    const u16* __restrict__ xBC, const float* __restrict__ conv_w,
    const float* __restrict__ conv_b, u16* __restrict__ xact)
{
    int o = blockIdx.x * 256 + threadIdx.x;   // MROWS/CRPT * 128 total
    int c0 = (o & 127) * 8;
    int rg = o >> 7;
    int row0 = rg * CRPT;
    int l0 = row0 & (SEQ - 1);                // SEQ % CRPT == 0: no seq crossing

    float4 wv[8];
    #pragma unroll
    for (int j = 0; j < 8; ++j)
        wv[j] = *(const float4*)(conv_w + (c0 + j) * 4);
    float bias[8];
    {
        float4 b0 = *(const float4*)(conv_b + c0);
        float4 b1 = *(const float4*)(conv_b + c0 + 4);
        bias[0]=b0.x; bias[1]=b0.y; bias[2]=b0.z; bias[3]=b0.w;
        bias[4]=b1.x; bias[5]=b1.y; bias[6]=b1.z; bias[7]=b1.w;
    }

    float win[3][8];
    #pragma unroll
    for (int k = 0; k < 3; ++k) {
        if (l0 - 3 + k < 0) {
            #pragma unroll
            for (int j = 0; j < 8; ++j) win[k][j] = 0.f;
        } else {
            gload8f(xBC + (size_t)(row0 - 3 + k) * NPROJ + c0, win[k]);
        }
    }
    #pragma unroll
    for (int r = 0; r < CRPT; ++r) {
        float cur[8];
        gload8f(xBC + (size_t)(row0 + r) * NPROJ + c0, cur);
        u16 outv[8];
        #pragma unroll
        for (int j = 0; j < 8; ++j) {
            float acc = bias[j]
                + win[0][j] * wv[j].x + win[1][j] * wv[j].y
                + win[2][j] * wv[j].z + cur[j]    * wv[j].w;
            outv[j] = f2bf(silu_f(acc));
        }
        *(bf16x8*)(xact + (size_t)(row0 + r) * DINNER + c0) = *(bf16x8*)outv;
        #pragma unroll
        for (int j = 0; j < 8; ++j) {
            win[0][j] = win[1][j]; win[1][j] = win[2][j]; win[2][j] = cur[j];
        }
    }
}

// ---------------------------------------------------------------------------
// Pass A: intra-chunk SSD.  Grid (dg=16, c=64, b=4); 256 threads, 4 waves.
// S output bf16 (u16).
// ---------------------------------------------------------------------------
__global__ __launch_bounds__(256) void ssd_intra_k(
    const u16* __restrict__ xact, u16* __restrict__ xBC,
    u16* __restrict__ Sh, const float* __restrict__ apw,
    const float* __restrict__ ainv)
{
    __shared__ u16 Pl[64][72];       // P[t][n] = C_t a^t
    __shared__ u16 Ql[64][72];       // Q[s][n] = B_s a^-s, then Ghi[t][s]
    __shared__ u16 Gl[64][72];       // Glo[t][s]
    __shared__ u16 Qt[64][72];       // Qt[n][s] = B_s a^{63-s}
    __shared__ u16 Xt[64][72];       // X^T [d][s]

    const int dg = blockIdx.x, c = blockIdx.y, b = blockIdx.z;
    const int dcol = dg * 64;
    const int l0 = c * CLEN;
    const int tid = threadIdx.x;
    const int w = tid >> 6, lane = tid & 63;
    const int quad = lane >> 4, l16 = lane & 15;
    const int tstrip = 16 * w;

    // stage B/C -> P, Q, Qt
    {
        const int st_t = tid >> 3, st_n8 = (tid & 7) * 8;
        #pragma unroll
        for (int rep = 0; rep < 2; ++rep) {
            int t = rep * 32 + st_t;
            size_t row = (size_t)(b * SEQ + l0 + t) * NPROJ;
            float Bv[8], Cv[8];
            gload8f(xBC + row + 2048 + st_n8, Bv);
            gload8f(xBC + row + 2112 + st_n8, Cv);
            float4 aw0 = *(const float4*)&apw[t * 64 + st_n8];
            float4 aw1 = *(const float4*)&apw[t * 64 + st_n8 + 4];
            float4 ai0 = *(const float4*)&ainv[t * 64 + st_n8];
            float4 ai1 = *(const float4*)&ainv[t * 64 + st_n8 + 4];
            float4 ar0 = *(const float4*)&apw[(63 - t) * 64 + st_n8];
            float4 ar1 = *(const float4*)&apw[(63 - t) * 64 + st_n8 + 4];
            float aw[8] = {aw0.x,aw0.y,aw0.z,aw0.w,aw1.x,aw1.y,aw1.z,aw1.w};
            float ai[8] = {ai0.x,ai0.y,ai0.z,ai0.w,ai1.x,ai1.y,ai1.z,ai1.w};
            float ar[8] = {ar0.x,ar0.y,ar0.z,ar0.w,ar1.x,ar1.y,ar1.z,ar1.w};
            u16 p8[8], q8[8];
            #pragma unroll
            for (int j = 0; j < 8; ++j) {
                p8[j] = f2bf(Cv[j] * aw[j]);
                q8[j] = f2bf(Bv[j] * ai[j]);
            }
            *(bf16x8*)&Pl[t][st_n8] = *(bf16x8*)p8;
            *(bf16x8*)&Ql[t][st_n8] = *(bf16x8*)q8;
            #pragma unroll
            for (int j = 0; j < 8; ++j)
                Qt[st_n8 + j][t] = f2bf(Bv[j] * ar[j]);
        }
    }
    // stage X transposed
    {
        #pragma unroll
        for (int rep = 0; rep < 2; ++rep) {
            int idx = rep * 256 + tid;          // 0..511
            int xt_t = idx >> 3, xt_d8 = (idx & 7) * 8;
            float xv[8];
            gload8f(xact + (size_t)(b * SEQ + l0 + xt_t) * DINNER + dcol + xt_d8, xv);
            #pragma unroll
            for (int j = 0; j < 8; ++j) Xt[xt_d8 + j][xt_t] = f2bf(xv[j]);
        }
    }
    __syncthreads();

    // ---- G = P Q^T (per wave: 16-t strip) ----
    bf16x8 af0 = *(const bf16x8*)&Pl[tstrip + l16][0  + quad * 8];
    bf16x8 af1 = *(const bf16x8*)&Pl[tstrip + l16][32 + quad * 8];
    f32x4 g[4] = {};
    #pragma unroll
    for (int j4 = 0; j4 < 4; ++j4) {
        bf16x8 b0 = *(const bf16x8*)&Ql[j4 * 16 + l16][0  + quad * 8];
        bf16x8 b1 = *(const bf16x8*)&Ql[j4 * 16 + l16][32 + quad * 8];
        g[j4] = __builtin_amdgcn_mfma_f32_16x16x32_bf16(af0, b0, g[j4], 0, 0, 0);
        g[j4] = __builtin_amdgcn_mfma_f32_16x16x32_bf16(af1, b1, g[j4], 0, 0, 0);
    }
    __syncthreads();

    // ---- mask (s<=t) + hi/lo split: Ghi->Ql, Glo->Gl ----
    #pragma unroll
    for (int j4 = 0; j4 < 4; ++j4) {
        #pragma unroll
        for (int r = 0; r < 4; ++r) {
            int t = tstrip + quad * 4 + r;
            int s = j4 * 16 + l16;
            float val = (s <= t) ? g[j4][r] : 0.f;
            u16 hi = f2bf(val);
            Ql[t][s] = hi;
            Gl[t][s] = f2bf(val - bf2f(hi));
        }
    }
    __syncthreads();

    // ---- Y strip [16t x 64d] and S strip [16n x 64d] ----
    bf16x8 gh0 = *(const bf16x8*)&Ql[tstrip + l16][0  + quad * 8];
    bf16x8 gh1 = *(const bf16x8*)&Ql[tstrip + l16][32 + quad * 8];
    bf16x8 gl0 = *(const bf16x8*)&Gl[tstrip + l16][0  + quad * 8];
    bf16x8 gl1 = *(const bf16x8*)&Gl[tstrip + l16][32 + quad * 8];
    bf16x8 qt0 = *(const bf16x8*)&Qt[tstrip + l16][0  + quad * 8];
    bf16x8 qt1 = *(const bf16x8*)&Qt[tstrip + l16][32 + quad * 8];

    #pragma unroll
    for (int dt = 0; dt < 4; ++dt) {
        bf16x8 x0 = *(const bf16x8*)&Xt[dt * 16 + l16][0  + quad * 8];
        bf16x8 x1 = *(const bf16x8*)&Xt[dt * 16 + l16][32 + quad * 8];
        f32x4 y = {};
        y = __builtin_amdgcn_mfma_f32_16x16x32_bf16(gh0, x0, y, 0, 0, 0);
        y = __builtin_amdgcn_mfma_f32_16x16x32_bf16(gh1, x1, y, 0, 0, 0);
        y = __builtin_amdgcn_mfma_f32_16x16x32_bf16(gl0, x0, y, 0, 0, 0);
        y = __builtin_amdgcn_mfma_f32_16x16x32_bf16(gl1, x1, y, 0, 0, 0);
        f32x4 s4 = {};
        s4 = __builtin_amdgcn_mfma_f32_16x16x32_bf16(qt0, x0, s4, 0, 0, 0);
        s4 = __builtin_amdgcn_mfma_f32_16x16x32_bf16(qt1, x1, s4, 0, 0, 0);
        #pragma unroll
        for (int r = 0; r < 4; ++r) {
            int t = tstrip + quad * 4 + r;       // y row
            xBC[(size_t)(b * SEQ + l0 + t) * NPROJ + dcol + dt * 16 + l16] = f2bf(y[r]);
            int n = tstrip + quad * 4 + r;       // s row
            Sh[((size_t)((b * NCHUNK + c) * 64 + n)) * 1024 + dcol + dt * 16 + l16] = f2bf(s4[r]);
        }
    }
}

// ---------------------------------------------------------------------------
// Pass B: inter-chunk state scan, in place on Sh (bf16, fp32 carry).
// ---------------------------------------------------------------------------
__global__ __launch_bounds__(256) void state_scan_k(
    u16* __restrict__ Sh, const float* __restrict__ l2a)
{
    int gid = blockIdx.x * 256 + threadIdx.x;    // 262144 total
    int b = gid >> 16, r = gid & 65535, n = r >> 10;
    float a64 = exp2f(64.f * l2a[n]);
    float v = 0.f;
    size_t base = ((size_t)b << 22) + r;
    for (int c = 0; c < NCHUNK; ++c) {
        size_t addr = base + ((size_t)c << 16);
        float s = bf2f(Sh[addr]);
        Sh[addr] = f2bf(v);
        v = fmaf(v, a64, s);
    }
}

// ---------------------------------------------------------------------------
// Pass C: inter-chunk correction (high-occupancy, round-3 structure, bf16 Sh).
// Grid (dg=16, c=64, b=4); 256 threads, 4 waves.
// ---------------------------------------------------------------------------
__global__ __launch_bounds__(256) void ssd_inter_k(
    u16* __restrict__ xBC, const u16* __restrict__ Sh,
    const float* __restrict__ apw, const float* __restrict__ l2a)
{
    __shared__ u16 Pl[64][72];       // P[t][n]
    __shared__ u16 Vt[64][72];       // (a*V)[d][n]

    const int dg = blockIdx.x, c = blockIdx.y, b = blockIdx.z;
    const int dcol = dg * 64;
    const int l0 = c * CLEN;
    const int tid = threadIdx.x;
    const int w = tid >> 6, lane = tid & 63;
    const int quad = lane >> 4, l16 = lane & 15;
    const int tstrip = 16 * w;

    // stage P
    {
        const int st_t = tid >> 3, st_n8 = (tid & 7) * 8;
        #pragma unroll
        for (int rep = 0; rep < 2; ++rep) {
            int t = rep * 32 + st_t;
            float Cv[8];
            gload8f(xBC + (size_t)(b * SEQ + l0 + t) * NPROJ + 2112 + st_n8, Cv);
            float4 aw0 = *(const float4*)&apw[t * 64 + st_n8];
            float4 aw1 = *(const float4*)&apw[t * 64 + st_n8 + 4];
            float aw[8] = {aw0.x,aw0.y,aw0.z,aw0.w,aw1.x,aw1.y,aw1.z,aw1.w};
            u16 p8[8];
            #pragma unroll
            for (int j = 0; j < 8; ++j) p8[j] = f2bf(Cv[j] * aw[j]);
            *(bf16x8*)&Pl[t][st_n8] = *(bf16x8*)p8;
        }
    }
    // stage aV transposed (bf16 Sh read, vector 16B)
    {
        #pragma unroll
        for (int rep = 0; rep < 2; ++rep) {
            int idx = rep * 256 + tid;          // 0..511
            int vn = idx >> 3, vd8 = (idx & 7) * 8;
            float an = exp2f(l2a[vn]);
            bf16x8 vv = *(const bf16x8*)&Sh[((size_t)((b * NCHUNK + c) * 64 + vn)) * 1024 + dcol + vd8];
            #pragma unroll
            for (int j = 0; j < 8; ++j) Vt[vd8 + j][vn] = f2bf(an * bf2f((u16)vv[j]));
        }
    }
    __syncthreads();

    bf16x8 af0 = *(const bf16x8*)&Pl[tstrip + l16][0  + quad * 8];
    bf16x8 af1 = *(const bf16x8*)&Pl[tstrip + l16][32 + quad * 8];
    #pragma unroll
    for (int dt = 0; dt < 4; ++dt) {
        bf16x8 hb0 = *(const bf16x8*)&Vt[dt * 16 + l16][0  + quad * 8];
        bf16x8 hb1 = *(const bf16x8*)&Vt[dt * 16 + l16][32 + quad * 8];
        f32x4 y = {};
        y = __builtin_amdgcn_mfma_f32_16x16x32_bf16(af0, hb0, y, 0, 0, 0);
        y = __builtin_amdgcn_mfma_f32_16x16x32_bf16(af1, hb1, y, 0, 0, 0);
        #pragma unroll
        for (int r = 0; r < 4; ++r) {
            int t = tstrip + quad * 4 + r;
            size_t addr = (size_t)(b * SEQ + l0 + t) * NPROJ + dcol + dt * 16 + l16;
            xBC[addr] = f2bf(bf2f(xBC[addr]) + y[r]);
        }
    }
}

// ---------------------------------------------------------------------------
// Gate (y * silu(z)) + LayerNorm over 1024 channels.  One block per row.
// ---------------------------------------------------------------------------
__global__ __launch_bounds__(256) void gate_k(
    const u16* __restrict__ xBC, const float* __restrict__ ln_w,
    const float* __restrict__ ln_b, u16* __restrict__ yn)
{
    __shared__ float r1[4], r2[4];
    const int row = blockIdx.x;
    const int tid = threadIdx.x;
    const int lane = tid & 63, wid = tid >> 6;
    const size_t base = (size_t)row * NPROJ;

    float gv[4];
    {
        const ushort4 yv = *(const ushort4*)(xBC + base + tid * 4);
        const ushort4 zv = *(const ushort4*)(xBC + base + 1024 + tid * 4);
        gv[0] = bf2f(yv.x) * silu_f(bf2f(zv.x));
        gv[1] = bf2f(yv.y) * silu_f(bf2f(zv.y));
        gv[2] = bf2f(yv.z) * silu_f(bf2f(zv.z));
        gv[3] = bf2f(yv.w) * silu_f(bf2f(zv.w));
    }
    float ps = gv[0] + gv[1] + gv[2] + gv[3];
    float pq = gv[0]*gv[0] + gv[1]*gv[1] + gv[2]*gv[2] + gv[3]*gv[3];
    #pragma unroll
    for (int off = 1; off < 64; off <<= 1) {
        ps += __shfl_xor(ps, off);
        pq += __shfl_xor(pq, off);
    }
    if (lane == 0) { r1[wid] = ps; r2[wid] = pq; }
    __syncthreads();
    float ts = r1[0] + r1[1] + r1[2] + r1[3];
    float tq = r2[0] + r2[1] + r2[2] + r2[3];
    float mu = ts * (1.0f / DINNER);
    float var = tq * (1.0f / DINNER) - mu * mu;
    float inv = rsqrtf(var + 1e-5f);

    u16 outv[4];
    #pragma unroll
    for (int j = 0; j < 4; ++j) {
        int c = tid * 4 + j;
        float v = (gv[j] - mu) * inv * ln_w[c] + ln_b[c];
        outv[j] = f2bf(v);
    }
    *(ushort4*)(yn + (size_t)row * DINNER + tid * 4) = *(ushort4*)outv;
}

// ---------------------------------------------------------------------------
extern "C" void kernel_launch(void* const* d_in, const int* in_sizes, int n_in,
                              void* d_out, int out_size, void* d_ws, size_t ws_size,
                              hipStream_t stream) {
    const float* x   = (const float*)d_in[0];
    const float* w1  = (const float*)d_in[1];
    const float* cw  = (const float*)d_in[2];
    const float* cb  = (const float*)d_in[3];
    const float* ap  = (const float*)d_in[4];
    const float* lnw = (const float*)d_in[5];
    const float* lnb = (const float*)d_in[6];
    const float* w2  = (const float*)d_in[7];
    float* out = (float*)d_out;

    // ws layout (~107 MiB):
    u16* xBC   = (u16*)d_ws;                             // MROWS x 2176
    u16* xact  = xBC + (size_t)MROWS * NPROJ;            // MROWS x 1024 (x_bf alias)
    u16* x_bf  = xact;                                   // dead once conv writes xact
    u16* w2_bf = xact + (size_t)MROWS * DINNER;          // 1024x1024
    float* l2a  = (float*)(w2_bf + (size_t)DMODEL * DINNER);  // 64
    float* apw  = l2a + 64;                              // 64x64
    float* ainv = apw + 4096;                            // 64x64
    // w1p (padded weights, 4.7MB) then Sh (bf16 S/V, 33.5MB) park in d_out:
    // w1p dead after gemm1; Sh written by pass A, consumed by ssd_inter
    // before gemm2 overwrites d_out with the final output.
    u16* w1p = (u16*)d_out;                              // 2304x1024 bf16
    u16* Sh  = (u16*)d_out;                              // 4 x 64 x 64 x 1024 bf16

    cast_f2b<<<(MROWS * DMODEL / 8) / 256, 256, 0, stream>>>(x, x_bf, MROWS * DMODEL / 8);
    cast_w1p_k<<<(NPAD * DMODEL / 8) / 256, 256, 0, stream>>>(w1, w1p);
    cast_f2b<<<(DMODEL * DINNER / 8) / 256, 256, 0, stream>>>(w2, w2_bf, DMODEL * DINNER / 8);
    tables_k<<<1, 256, 0, stream>>>(ap, l2a, apw, ainv);

    gemm8p_k<u16, 9, NPROJ, NPROJ><<<9 * 64, 512, 0, stream>>>(x_bf, w1p, xBC);
    conv_k<<<(MROWS / CRPT * 128) / 256, 256, 0, stream>>>(xBC, cw, cb, xact);

    ssd_intra_k<<<dim3(16, NCHUNK, BATCH), 256, 0, stream>>>(xact, xBC, Sh, apw, ainv);
    state_scan_k<<<1024, 256, 0, stream>>>(Sh, l2a);
    ssd_inter_k<<<dim3(16, NCHUNK, BATCH), 256, 0, stream>>>(xBC, Sh, apw, l2a);

    gate_k<<<MROWS, 256, 0, stream>>>(xBC, lnw, lnb, xact);
    gemm8p_k<float, 4, DMODEL, DMODEL><<<4 * 64, 512, 0, stream>>>(xact, w2_bf, out);
}